// Round 12
// baseline (229.271 us; speedup 1.0000x reference)
//
#include <hip/hip_runtime.h>

// WaveNet gated residual block, MI355X bf16-MFMA (v12 = v11 + PHASE ABLATION).
// v11 (TT=128) = best: k12 117us, total 106us, clean traffic, but no counter
// localizes the ~75us above roofline. This round: 4 named variants of the
// same body (stage / +k1+gate / +k2-nostore / full) dispatched sequentially.
// Marginal times localize the cost empirically. full runs LAST -> d_out valid.
// anti-DCE: asm "memory" clobbers for LDS-write-only variants; asm "v" keeps
// for store-less k2 (guide rule #17).

#define NB 8
#define NT 16000
#define CIN 128
#define CCOND 80
#define CCP 96
#define TT 128
#define NROW 136   // TT + 8 halo

typedef __attribute__((ext_vector_type(8))) __bf16 bf16x8;
typedef __attribute__((ext_vector_type(4))) float f32x4;
typedef __attribute__((ext_vector_type(4))) unsigned short u16x4;
typedef __attribute__((ext_vector_type(4))) unsigned int u32x4;

__device__ __forceinline__ unsigned short f2bf(float f) {
  unsigned int u = __float_as_uint(f);
  return (unsigned short)((u + 0x7fffu + ((u >> 16) & 1u)) >> 16);  // RNE
}
__device__ __forceinline__ bf16x8 ldb8(const unsigned short* p) {
  return *reinterpret_cast<const bf16x8*>(p);
}

// ---- pack weights to bf16 [M][K] ----
__global__ void pack_weights(const float* __restrict__ wc, const float* __restrict__ wcd,
                             const float* __restrict__ wo, const float* __restrict__ wsk,
                             unsigned short* __restrict__ wpc,
                             unsigned short* __restrict__ wpcd,
                             unsigned short* __restrict__ wp2)
{
  int idx = blockIdx.x * 256 + threadIdx.x;
  if (idx < 98304) {
    int o = idx / 384, k = idx - o * 384;
    int tap = k >> 7, c = k & 127;
    wpc[idx] = f2bf(wc[(o * 128 + c) * 3 + tap]);
  } else if (idx < 122880) {
    int i = idx - 98304;
    int o = i / 96, k = i - o * 96;
    wpcd[i] = f2bf(k < CCOND ? wcd[o * CCOND + k] : 0.f);
  } else if (idx < 172032) {
    int i = idx - 122880;
    int m = i >> 7, k = i & 127;
    wp2[i] = f2bf(m < 128 ? wo[m * 128 + k] : wsk[(m - 128) * 128 + k]);
  }
}

// MODE bits: 1 = k1+gate, 2 = k2 compute, 4 = global stores
template<int MODE>
__device__ __forceinline__ void k12_body(
    const unsigned short* __restrict__ wpc, const unsigned short* __restrict__ wpcd,
    const unsigned short* __restrict__ wp2,
    const float* __restrict__ in, const float* __restrict__ cond,
    const float* __restrict__ bconv, const float* __restrict__ bout,
    const float* __restrict__ bskip, float* __restrict__ out)
{
  __shared__ u32x4 ldsX_[2176];  // X tile [136 rows][16 granules x 16B], swizzled
  __shared__ u32x4 ldsU_[2048];  // UNION: cond [128][12x16B] / z [128][16x16B]
  char* ldsX = (char*)ldsX_;
  char* ldsU = (char*)ldsU_;

  int b = blockIdx.y;
  int t0 = blockIdx.x * TT;
  int tid = threadIdx.x;
  int lane = tid & 63, w = tid >> 6;
  int l15 = lane & 15, g = lane >> 4;

  // ---- stage X ----
  #pragma unroll
  for (int rep = 0; rep < 5; ++rep) {
    int gi = rep * 512 + tid;
    if (gi < 16 * NROW) {
      int gch = gi / NROW;
      int row = gi - gch * NROW;
      int t = t0 - 8 + row;
      u32x4 pk = {};
      if (t >= 0) {
        const float* src = &in[((size_t)b * CIN + gch * 8) * NT + t];
        #pragma unroll
        for (int p = 0; p < 4; ++p) {
          float v0 = src[(size_t)(2 * p) * NT];
          float v1 = src[(size_t)(2 * p + 1) * NT];
          pk[p] = (unsigned)f2bf(v0) | ((unsigned)f2bf(v1) << 16);
        }
      }
      *reinterpret_cast<u32x4*>(&ldsX[row * 256 + ((gch ^ (row & 7)) << 4)]) = pk;
    }
  }
  // ---- stage cond ----
  #pragma unroll
  for (int rep = 0; rep < 3; ++rep) {
    int gi = rep * 512 + tid;
    int gch = gi >> 7;
    int row = gi & 127;
    u32x4 pk = {};
    if (gch < 10) {
      const float* src = &cond[((size_t)b * CCOND + gch * 8) * NT + t0 + row];
      #pragma unroll
      for (int p = 0; p < 4; ++p) {
        float v0 = src[(size_t)(2 * p) * NT];
        float v1 = src[(size_t)(2 * p + 1) * NT];
        pk[p] = (unsigned)f2bf(v0) | ((unsigned)f2bf(v1) << 16);
      }
    }
    *reinterpret_cast<u32x4*>(&ldsU[row * 192 + ((gch ^ (row & 3)) << 4)]) = pk;
  }
  __syncthreads();

  if constexpr ((MODE & 1) == 0) {
    asm volatile("" ::: "memory");   // keep LDS writes observable; stop here
    return;
  } else {

  // ---- k1 ----
  int rt = 16 * w + l15, rs = 128 + 16 * w + l15;
  f32x4 at[8] = {}, as_[8] = {};

  #pragma unroll
  for (int gg = 0; gg < 5; ++gg) {
    bf16x8 wt[3], wss[3];
    #pragma unroll
    for (int q = 0; q < 3; ++q) {
      int s = gg * 3 + q;
      if (s < 12) {
        int tap = s >> 2, kc = s & 3;
        wt[q]  = ldb8(&wpc[(size_t)rt * 384 + tap * 128 + kc * 32 + g * 8]);
        wss[q] = ldb8(&wpc[(size_t)rs * 384 + tap * 128 + kc * 32 + g * 8]);
      } else {
        int kc = s - 12;
        wt[q]  = ldb8(&wpcd[(size_t)rt * CCP + kc * 32 + g * 8]);
        wss[q] = ldb8(&wpcd[(size_t)rs * CCP + kc * 32 + g * 8]);
      }
    }
    __builtin_amdgcn_sched_barrier(0);
    #pragma unroll
    for (int q = 0; q < 3; ++q) {
      int s = gg * 3 + q;
      if (s < 12) {
        int tap = s >> 2, kc = s & 3;
        int ck = kc * 4 + g;
        #pragma unroll
        for (int nf = 0; nf < 8; ++nf) {
          int tl = nf * 16 + l15 + tap * 4;
          bf16x8 bfr = *reinterpret_cast<const bf16x8*>(&ldsX[tl * 256 + ((ck ^ (tl & 7)) << 4)]);
          at[nf]  = __builtin_amdgcn_mfma_f32_16x16x32_bf16(wt[q],  bfr, at[nf],  0, 0, 0);
          as_[nf] = __builtin_amdgcn_mfma_f32_16x16x32_bf16(wss[q], bfr, as_[nf], 0, 0, 0);
        }
      } else {
        int kc = s - 12;
        int ck = kc * 4 + g;
        #pragma unroll
        for (int nf = 0; nf < 8; ++nf) {
          int r = nf * 16 + l15;
          bf16x8 bfr = *reinterpret_cast<const bf16x8*>(&ldsU[r * 192 + ((ck ^ (r & 3)) << 4)]);
          at[nf]  = __builtin_amdgcn_mfma_f32_16x16x32_bf16(wt[q],  bfr, at[nf],  0, 0, 0);
          as_[nf] = __builtin_amdgcn_mfma_f32_16x16x32_bf16(wss[q], bfr, as_[nf], 0, 0, 0);
        }
      }
    }
  }

  float btv[4], bsv[4];
  #pragma unroll
  for (int j = 0; j < 4; ++j) {
    btv[j] = bconv[16 * w + g * 4 + j];
    bsv[j] = bconv[128 + 16 * w + g * 4 + j];
  }

  bf16x8 wk2buf[2][4];
  if constexpr (MODE & 2) {
    #pragma unroll
    for (int kc = 0; kc < 4; ++kc)
      wk2buf[0][kc] = ldb8(&wp2[(size_t)(48 * w + l15) * 128 + kc * 32 + g * 8]);
  }

  __syncthreads();

  // ---- gate -> z in LDS ----
  {
    int cg = 2 * w + (g >> 1);
    int off = (g & 1) * 8;
    #pragma unroll
    for (int nf = 0; nf < 8; ++nf) {
      int tl = nf * 16 + l15;
      u16x4 pk;
      #pragma unroll
      for (int j = 0; j < 4; ++j) {
        float a = at[nf][j] + btv[j];
        float s = as_[nf][j] + bsv[j];
        float z = (1.f - 2.f / (1.f + __expf(2.f * a))) * (1.f / (1.f + __expf(-s)));
        pk[j] = f2bf(z);
      }
      *reinterpret_cast<u16x4*>(&ldsU[tl * 256 + ((cg ^ (tl & 7)) << 4) + off]) = pk;
    }
  }
  __syncthreads();

  if constexpr ((MODE & 2) == 0) {
    asm volatile("" ::: "memory");   // keep z writes; stop here
    return;
  } else {

  // ---- k2 ----
  float* skipp = out + (size_t)NB * 128 * NT;
  #pragma unroll
  for (int mf = 0; mf < 3; ++mf) {
    bf16x8* wcur = wk2buf[mf & 1];
    bf16x8* wnx  = wk2buf[(mf + 1) & 1];
    if (mf < 2) {
      #pragma unroll
      for (int kc = 0; kc < 4; ++kc)
        wnx[kc] = ldb8(&wp2[(size_t)(48 * w + 16 * (mf + 1) + l15) * 128 + kc * 32 + g * 8]);
    }
    __builtin_amdgcn_sched_barrier(0);
    f32x4 am[8] = {};
    #pragma unroll
    for (int kc = 0; kc < 4; ++kc) {
      #pragma unroll
      for (int nf = 0; nf < 8; ++nf) {
        int r = nf * 16 + l15;
        bf16x8 bfr = *reinterpret_cast<const bf16x8*>(&ldsU[r * 256 + (((kc * 4 + g) ^ (r & 7)) << 4)]);
        am[nf] = __builtin_amdgcn_mfma_f32_16x16x32_bf16(wcur[kc], bfr, am[nf], 0, 0, 0);
      }
    }
    int mrow = 48 * w + 16 * mf + g * 4;
    #pragma unroll
    for (int j = 0; j < 4; ++j) {
      int m = mrow + j;
      float bv;
      float* basep;
      if (m < 128) { bv = bout[m];        basep = out   + ((size_t)b * 128 + m) * NT; }
      else         { bv = bskip[m - 128]; basep = skipp + ((size_t)b * 256 + (m - 128)) * NT; }
      #pragma unroll
      for (int nf = 0; nf < 8; ++nf) {
        float v = am[nf][j] + bv;
        if constexpr (MODE & 4) basep[t0 + nf * 16 + l15] = v;
        else                    asm volatile("" :: "v"(v));   // keep, no store
      }
    }
  }
  } // MODE & 2
  } // MODE & 1
}

__global__ __launch_bounds__(512, 4) void k12_abl_stage(
    const unsigned short* __restrict__ wpc, const unsigned short* __restrict__ wpcd,
    const unsigned short* __restrict__ wp2,
    const float* __restrict__ in, const float* __restrict__ cond,
    const float* __restrict__ bconv, const float* __restrict__ bout,
    const float* __restrict__ bskip, float* __restrict__ out)
{ k12_body<0>(wpc, wpcd, wp2, in, cond, bconv, bout, bskip, out); }

__global__ __launch_bounds__(512, 4) void k12_abl_k1gate(
    const unsigned short* __restrict__ wpc, const unsigned short* __restrict__ wpcd,
    const unsigned short* __restrict__ wp2,
    const float* __restrict__ in, const float* __restrict__ cond,
    const float* __restrict__ bconv, const float* __restrict__ bout,
    const float* __restrict__ bskip, float* __restrict__ out)
{ k12_body<1>(wpc, wpcd, wp2, in, cond, bconv, bout, bskip, out); }

__global__ __launch_bounds__(512, 4) void k12_abl_nostore(
    const unsigned short* __restrict__ wpc, const unsigned short* __restrict__ wpcd,
    const unsigned short* __restrict__ wp2,
    const float* __restrict__ in, const float* __restrict__ cond,
    const float* __restrict__ bconv, const float* __restrict__ bout,
    const float* __restrict__ bskip, float* __restrict__ out)
{ k12_body<3>(wpc, wpcd, wp2, in, cond, bconv, bout, bskip, out); }

__global__ __launch_bounds__(512, 4) void k12_full(
    const unsigned short* __restrict__ wpc, const unsigned short* __restrict__ wpcd,
    const unsigned short* __restrict__ wp2,
    const float* __restrict__ in, const float* __restrict__ cond,
    const float* __restrict__ bconv, const float* __restrict__ bout,
    const float* __restrict__ bskip, float* __restrict__ out)
{ k12_body<7>(wpc, wpcd, wp2, in, cond, bconv, bout, bskip, out); }

extern "C" void kernel_launch(void* const* d_in, const int* in_sizes, int n_in,
                              void* d_out, int out_size, void* d_ws, size_t ws_size,
                              hipStream_t stream)
{
  const float* input = (const float*)d_in[0];
  const float* cond  = (const float*)d_in[1];
  const float* wconv = (const float*)d_in[2];
  const float* bconv = (const float*)d_in[3];
  const float* wcond = (const float*)d_in[4];
  const float* wout  = (const float*)d_in[5];
  const float* boutp = (const float*)d_in[6];
  const float* wskip = (const float*)d_in[7];
  const float* bskip = (const float*)d_in[8];
  float* out = (float*)d_out;

  unsigned short* wpc  = (unsigned short*)d_ws;
  unsigned short* wpcd = wpc + 98304;
  unsigned short* wp2  = wpcd + 24576;

  pack_weights<<<672, 256, 0, stream>>>(wconv, wcond, wout, wskip, wpc, wpcd, wp2);
  dim3 grid(NT / TT, NB);
  // ablation dispatches (measurement only; do not touch d_out)
  k12_abl_stage  <<<grid, 512, 0, stream>>>(wpc, wpcd, wp2, input, cond, bconv, boutp, bskip, out);
  k12_abl_k1gate <<<grid, 512, 0, stream>>>(wpc, wpcd, wp2, input, cond, bconv, boutp, bskip, out);
  k12_abl_nostore<<<grid, 512, 0, stream>>>(wpc, wpcd, wp2, input, cond, bconv, boutp, bskip, out);
  // real output, runs last
  k12_full       <<<grid, 512, 0, stream>>>(wpc, wpcd, wp2, input, cond, bconv, boutp, bskip, out);
}

// Round 13
// 109.085 us; speedup vs baseline: 2.1018x; 2.1018x over previous
//
#include <hip/hip_runtime.h>

// WaveNet gated residual block, MI355X bf16-MFMA implementation (v13).
// v13 = v11 (TT=128, fused transpose+k1+gate+k2, 117us) with k2 switched to
// 32x32x16 MFMA. R12 ablation localized ~60-75us in {k2+stores}; the 16x16
// D-layout forced 4x64B scattered segments per store instr. The 32x32 D
// (col=lane&31, row=(reg&3)+8(reg>>2)+4(lane>>5), guide-verified) gives
// 2x128B contiguous segments -> half the L2 write transactions, full lines.
// k2 tiles processed in same-m32 pairs: shared A-frags + bias, two
// independent acc chains (hides MFMA latency). k1/gate/z unchanged.

#define NB 8
#define NT 16000
#define CIN 128
#define CCOND 80
#define CCP 96
#define TT 128
#define NROW 136   // TT + 8 halo

typedef __attribute__((ext_vector_type(8))) __bf16 bf16x8;
typedef __attribute__((ext_vector_type(4))) float f32x4;
typedef __attribute__((ext_vector_type(16))) float f32x16;
typedef __attribute__((ext_vector_type(4))) unsigned short u16x4;
typedef __attribute__((ext_vector_type(4))) unsigned int u32x4;

__device__ __forceinline__ unsigned short f2bf(float f) {
  unsigned int u = __float_as_uint(f);
  return (unsigned short)((u + 0x7fffu + ((u >> 16) & 1u)) >> 16);  // RNE
}
__device__ __forceinline__ bf16x8 ldb8(const unsigned short* p) {
  return *reinterpret_cast<const bf16x8*>(p);
}

// ---- pack weights to bf16 [M][K] ----
__global__ void pack_weights(const float* __restrict__ wc, const float* __restrict__ wcd,
                             const float* __restrict__ wo, const float* __restrict__ wsk,
                             unsigned short* __restrict__ wpc,   // [256][384] k=tap*128+c
                             unsigned short* __restrict__ wpcd,  // [256][96]  zero-pad k>=80
                             unsigned short* __restrict__ wp2)   // [384][128] rows 0-127 Wout, 128-383 Wskip
{
  int idx = blockIdx.x * 256 + threadIdx.x;
  if (idx < 98304) {
    int o = idx / 384, k = idx - o * 384;
    int tap = k >> 7, c = k & 127;
    wpc[idx] = f2bf(wc[(o * 128 + c) * 3 + tap]);
  } else if (idx < 122880) {
    int i = idx - 98304;
    int o = i / 96, k = i - o * 96;
    wpcd[i] = f2bf(k < CCOND ? wcd[o * CCOND + k] : 0.f);
  } else if (idx < 172032) {
    int i = idx - 122880;
    int m = i >> 7, k = i & 127;
    wp2[i] = f2bf(m < 128 ? wo[m * 128 + k] : wsk[(m - 128) * 128 + k]);
  }
}

// ======================= FUSED transpose+k1+k2 (v13) =========================
__global__ __launch_bounds__(512, 4) void k12_fused(
    const unsigned short* __restrict__ wpc, const unsigned short* __restrict__ wpcd,
    const unsigned short* __restrict__ wp2,
    const float* __restrict__ in, const float* __restrict__ cond,
    const float* __restrict__ bconv, const float* __restrict__ bout,
    const float* __restrict__ bskip, float* __restrict__ out)
{
  __shared__ u32x4 ldsX_[2176];  // X tile [136 t-rows][16 granules x 16B], swizzled
  __shared__ u32x4 ldsU_[2048];  // UNION: cond [128][12x16B] / z [128][16x16B]
  char* ldsX = (char*)ldsX_;
  char* ldsU = (char*)ldsU_;

  int b = blockIdx.y;
  int t0 = blockIdx.x * TT;
  int tid = threadIdx.x;
  int lane = tid & 63, w = tid >> 6;            // w 0..7
  int l15 = lane & 15, g = lane >> 4;

  // ---- stage X from raw f32 (lanes = consecutive t: coalesced 256B) ----
  #pragma unroll
  for (int rep = 0; rep < 5; ++rep) {
    int gi = rep * 512 + tid;
    if (gi < 16 * NROW) {
      int gch = gi / NROW;
      int row = gi - gch * NROW;
      int t = t0 - 8 + row;
      u32x4 pk = {};
      if (t >= 0) {
        const float* src = &in[((size_t)b * CIN + gch * 8) * NT + t];
        #pragma unroll
        for (int p = 0; p < 4; ++p) {
          float v0 = src[(size_t)(2 * p) * NT];
          float v1 = src[(size_t)(2 * p + 1) * NT];
          pk[p] = (unsigned)f2bf(v0) | ((unsigned)f2bf(v1) << 16);
        }
      }
      *reinterpret_cast<u32x4*>(&ldsX[row * 256 + ((gch ^ (row & 7)) << 4)]) = pk;
    }
  }
  // ---- stage cond (granules 10,11 zero pad) ----
  #pragma unroll
  for (int rep = 0; rep < 3; ++rep) {
    int gi = rep * 512 + tid;
    int gch = gi >> 7;
    int row = gi & 127;
    u32x4 pk = {};
    if (gch < 10) {
      const float* src = &cond[((size_t)b * CCOND + gch * 8) * NT + t0 + row];
      #pragma unroll
      for (int p = 0; p < 4; ++p) {
        float v0 = src[(size_t)(2 * p) * NT];
        float v1 = src[(size_t)(2 * p + 1) * NT];
        pk[p] = (unsigned)f2bf(v0) | ((unsigned)f2bf(v1) << 16);
      }
    }
    *reinterpret_cast<u32x4*>(&ldsU[row * 192 + ((gch ^ (row & 3)) << 4)]) = pk;
  }
  __syncthreads();

  // ---- k1 (16x16x32): wave w owns rows 16w..+15 (tanh), 128+16w.. (sigmoid) ----
  int rt = 16 * w + l15, rs = 128 + 16 * w + l15;
  f32x4 at[8] = {}, as_[8] = {};

  #pragma unroll
  for (int gg = 0; gg < 5; ++gg) {
    bf16x8 wt[3], wss[3];
    #pragma unroll
    for (int q = 0; q < 3; ++q) {
      int s = gg * 3 + q;
      if (s < 12) {
        int tap = s >> 2, kc = s & 3;
        wt[q]  = ldb8(&wpc[(size_t)rt * 384 + tap * 128 + kc * 32 + g * 8]);
        wss[q] = ldb8(&wpc[(size_t)rs * 384 + tap * 128 + kc * 32 + g * 8]);
      } else {
        int kc = s - 12;
        wt[q]  = ldb8(&wpcd[(size_t)rt * CCP + kc * 32 + g * 8]);
        wss[q] = ldb8(&wpcd[(size_t)rs * CCP + kc * 32 + g * 8]);
      }
    }
    __builtin_amdgcn_sched_barrier(0);
    #pragma unroll
    for (int q = 0; q < 3; ++q) {
      int s = gg * 3 + q;
      if (s < 12) {
        int tap = s >> 2, kc = s & 3;
        int ck = kc * 4 + g;
        #pragma unroll
        for (int nf = 0; nf < 8; ++nf) {
          int tl = nf * 16 + l15 + tap * 4;
          bf16x8 bfr = *reinterpret_cast<const bf16x8*>(&ldsX[tl * 256 + ((ck ^ (tl & 7)) << 4)]);
          at[nf]  = __builtin_amdgcn_mfma_f32_16x16x32_bf16(wt[q],  bfr, at[nf],  0, 0, 0);
          as_[nf] = __builtin_amdgcn_mfma_f32_16x16x32_bf16(wss[q], bfr, as_[nf], 0, 0, 0);
        }
      } else {
        int kc = s - 12;
        int ck = kc * 4 + g;
        #pragma unroll
        for (int nf = 0; nf < 8; ++nf) {
          int r = nf * 16 + l15;
          bf16x8 bfr = *reinterpret_cast<const bf16x8*>(&ldsU[r * 192 + ((ck ^ (r & 3)) << 4)]);
          at[nf]  = __builtin_amdgcn_mfma_f32_16x16x32_bf16(wt[q],  bfr, at[nf],  0, 0, 0);
          as_[nf] = __builtin_amdgcn_mfma_f32_16x16x32_bf16(wss[q], bfr, as_[nf], 0, 0, 0);
        }
      }
    }
  }

  float btv[4], bsv[4];
  #pragma unroll
  for (int j = 0; j < 4; ++j) {
    btv[j] = bconv[16 * w + g * 4 + j];
    bsv[j] = bconv[128 + 16 * w + g * 4 + j];
  }

  __syncthreads();   // cond region consumed; ldsU becomes z

  // ---- gate in-register -> z into swizzled ldsU [128 rows][256B] ----
  {
    int cg = 2 * w + (g >> 1);
    int off = (g & 1) * 8;
    #pragma unroll
    for (int nf = 0; nf < 8; ++nf) {
      int tl = nf * 16 + l15;
      u16x4 pk;
      #pragma unroll
      for (int j = 0; j < 4; ++j) {
        float a = at[nf][j] + btv[j];
        float s = as_[nf][j] + bsv[j];
        float z = (1.f - 2.f / (1.f + __expf(2.f * a))) * (1.f / (1.f + __expf(-s)));
        pk[j] = f2bf(z);
      }
      *reinterpret_cast<u16x4*>(&ldsU[tl * 256 + ((cg ^ (tl & 7)) << 4) + off]) = pk;
    }
  }
  __syncthreads();

  // ---- k2 (32x32x16): 48 output tiles (12 m32 x 4 t32); wave w owns 6,
  //      processed as 3 same-m32 pairs (shared A + bias, dual acc chains) ----
  float* skipp = out + (size_t)NB * 128 * NT;
  int l31 = lane & 31, half = (lane >> 5) * 4;
  #pragma unroll
  for (int pr = 0; pr < 3; ++pr) {
    int tid0 = w * 6 + pr * 2;
    int m32 = tid0 >> 2;                 // same for both tiles of the pair
    int t32a = tid0 & 3, t32b = t32a + 1;
    const float* bp;
    float* gbase;
    if (m32 < 4) { bp = bout + m32 * 32;
                   gbase = out + ((size_t)b * 128 + m32 * 32) * NT; }
    else         { bp = bskip + (m32 * 32 - 128);
                   gbase = skipp + ((size_t)b * 256 + (m32 * 32 - 128)) * NT; }
    float bv[16];
    #pragma unroll
    for (int j = 0; j < 16; ++j)
      bv[j] = bp[(j & 3) + 8 * (j >> 2) + half];

    f32x16 c0 = {}, c1 = {};
    int ta = t32a * 32 + l31, tb = t32b * 32 + l31;
    #pragma unroll
    for (int kc = 0; kc < 8; ++kc) {
      bf16x8 a = ldb8(&wp2[(size_t)(m32 * 32 + l31) * 128 + kc * 16 + (lane >> 5) * 8]);
      int gk = kc * 2 + (lane >> 5);
      bf16x8 b0 = *reinterpret_cast<const bf16x8*>(&ldsU[ta * 256 + ((gk ^ (ta & 7)) << 4)]);
      bf16x8 b1 = *reinterpret_cast<const bf16x8*>(&ldsU[tb * 256 + ((gk ^ (tb & 7)) << 4)]);
      c0 = __builtin_amdgcn_mfma_f32_32x32x16_bf16(a, b0, c0, 0, 0, 0);
      c1 = __builtin_amdgcn_mfma_f32_32x32x16_bf16(a, b1, c1, 0, 0, 0);
    }
    #pragma unroll
    for (int j = 0; j < 16; ++j) {
      int r = (j & 3) + 8 * (j >> 2) + half;
      float* rowp = gbase + (size_t)r * NT + t0;
      rowp[t32a * 32 + l31] = c0[j] + bv[j];   // 2x128B contiguous per instr
      rowp[t32b * 32 + l31] = c1[j] + bv[j];
    }
  }
}

extern "C" void kernel_launch(void* const* d_in, const int* in_sizes, int n_in,
                              void* d_out, int out_size, void* d_ws, size_t ws_size,
                              hipStream_t stream)
{
  const float* input = (const float*)d_in[0];
  const float* cond  = (const float*)d_in[1];
  const float* wconv = (const float*)d_in[2];
  const float* bconv = (const float*)d_in[3];
  const float* wcond = (const float*)d_in[4];
  const float* wout  = (const float*)d_in[5];
  const float* boutp = (const float*)d_in[6];
  const float* wskip = (const float*)d_in[7];
  const float* bskip = (const float*)d_in[8];
  float* out = (float*)d_out;

  unsigned short* wpc  = (unsigned short*)d_ws;     //  98304 elems
  unsigned short* wpcd = wpc + 98304;               //  24576 elems
  unsigned short* wp2  = wpcd + 24576;              //  49152 elems

  pack_weights<<<672, 256, 0, stream>>>(wconv, wcond, wout, wskip, wpc, wpcd, wp2);
  k12_fused<<<dim3(NT / TT, NB), 512, 0, stream>>>(wpc, wpcd, wp2, input, cond,
                                                   bconv, boutp, bskip, out);
}